// Round 3
// baseline (12735.630 us; speedup 1.0000x reference)
//
#include <hip/hip_runtime.h>
#include <stdint.h>

// ---------------- problem constants ----------------
#define T_STEPS 1000
#define B_SZ    32
#define NI      512
#define NH      1024
#define NO      256

#define NBLK    256   // scan blocks; block p owns SLICE=4 postsyn neurons x all 32 batches
#define SLICE   4

typedef unsigned long long u64;

// ---------------- ws layout (bytes) ----------------
#define OFF_IEXT 0ull
#define SZ_IEXT  ((unsigned long long)T_STEPS * B_SZ * NH * 4ull)   // 131,072,000
#define OFF_WP   (OFF_IEXT + SZ_IEXT)
#define SZ_WP    ((unsigned long long)NH * NH * 4ull)               // 4 MiB
#define OFF_RATE (OFF_WP + SZ_WP)
#define SZ_RATE  ((unsigned long long)B_SZ * NH * 4ull)             // 128 KiB
#define OFF_SYNC (OFF_RATE + SZ_RATE)
#define SZ_SYNC  16384ull   // 2 parities x 4 planes x 256 producers x u64

// ---------------- agent-scope helpers ----------------
__device__ __forceinline__ u64 ld64_agent(const u64* p) {
  return __hip_atomic_load(p, __ATOMIC_RELAXED, __HIP_MEMORY_SCOPE_AGENT);
}
__device__ __forceinline__ void st64_agent(u64* p, u64 v) {
  __hip_atomic_store(p, v, __ATOMIC_RELAXED, __HIP_MEMORY_SCOPE_AGENT);
}

// ---------------- kernel 1: pack W_rec into per-block slices ----------------
// WP[(p*1024 + i)*4 + jj] = W_rec[(4p+jj)*1024 + i]  -> 16 KB contiguous per block
__global__ __launch_bounds__(256) void prep_wp(const float* __restrict__ Wrec,
                                               float* __restrict__ WP) {
  const int p = blockIdx.x;
  const int t = threadIdx.x;
#pragma unroll
  for (int it = 0; it < 4; ++it) {
    const int i = it * 256 + t;
    float4 w;
    w.x = Wrec[(size_t)(SLICE * p + 0) * NH + i];
    w.y = Wrec[(size_t)(SLICE * p + 1) * NH + i];
    w.z = Wrec[(size_t)(SLICE * p + 2) * NH + i];
    w.w = Wrec[(size_t)(SLICE * p + 3) * NH + i];
    ((float4*)WP)[(size_t)p * NH + i] = w;
  }
}

// ---------------- kernel 2: I_ext = x @ W_in^T  (fp32 tiled) ----------------
// Kept fp32 on purpose: bf16 I_ext (~0.2 abs err on ~N(0,50) values) would flip
// threshold crossings and cascade through the recurrence past the absmax budget.
#define GBM 128
#define GBN 128
#define GBK 16
__global__ __launch_bounds__(256) void gemm_in(const float* __restrict__ X,
                                               const float* __restrict__ Win,
                                               float* __restrict__ I) {
  __shared__ float As[GBK][GBM + 4];
  __shared__ float Bs[GBK][GBN + 4];
  const int tid = threadIdx.x;
  const int m0 = blockIdx.x * GBM;
  const int n0 = blockIdx.y * GBN;
  const int tm = tid >> 4, tn = tid & 15;
  const int lr = tid >> 1, lk = (tid & 1) * 8;
  float acc[8][8] = {};
  for (int k0 = 0; k0 < NI; k0 += GBK) {
    float4 a0 = *(const float4*)&X[(size_t)(m0 + lr) * NI + k0 + lk];
    float4 a1 = *(const float4*)&X[(size_t)(m0 + lr) * NI + k0 + lk + 4];
    float4 b0 = *(const float4*)&Win[(size_t)(n0 + lr) * NI + k0 + lk];
    float4 b1 = *(const float4*)&Win[(size_t)(n0 + lr) * NI + k0 + lk + 4];
    As[lk + 0][lr] = a0.x; As[lk + 1][lr] = a0.y; As[lk + 2][lr] = a0.z; As[lk + 3][lr] = a0.w;
    As[lk + 4][lr] = a1.x; As[lk + 5][lr] = a1.y; As[lk + 6][lr] = a1.z; As[lk + 7][lr] = a1.w;
    Bs[lk + 0][lr] = b0.x; Bs[lk + 1][lr] = b0.y; Bs[lk + 2][lr] = b0.z; Bs[lk + 3][lr] = b0.w;
    Bs[lk + 4][lr] = b1.x; Bs[lk + 5][lr] = b1.y; Bs[lk + 6][lr] = b1.z; Bs[lk + 7][lr] = b1.w;
    __syncthreads();
#pragma unroll
    for (int k = 0; k < GBK; ++k) {
      float av[8], bv[8];
      *(float4*)&av[0] = *(const float4*)&As[k][tm * 8];
      *(float4*)&av[4] = *(const float4*)&As[k][tm * 8 + 4];
      *(float4*)&bv[0] = *(const float4*)&Bs[k][tn * 8];
      *(float4*)&bv[4] = *(const float4*)&Bs[k][tn * 8 + 4];
#pragma unroll
      for (int i2 = 0; i2 < 8; ++i2)
#pragma unroll
        for (int j2 = 0; j2 < 8; ++j2) acc[i2][j2] += av[i2] * bv[j2];
    }
    __syncthreads();
  }
#pragma unroll
  for (int i2 = 0; i2 < 8; ++i2) {
    float4 c0 = {acc[i2][0], acc[i2][1], acc[i2][2], acc[i2][3]};
    float4 c1 = {acc[i2][4], acc[i2][5], acc[i2][6], acc[i2][7]};
    *(float4*)&I[(size_t)(m0 + tm * 8 + i2) * NH + n0 + tn * 8] = c0;
    *(float4*)&I[(size_t)(m0 + tm * 8 + i2) * NH + n0 + tn * 8 + 4] = c1;
  }
}

// ---------------- kernel 3: persistent 1000-step scan ----------------
// Roles per block: wave 0 = all 128 neuron states (2/lane) + publisher (lane 0);
// wave 1 = dedicated tag poller; all 4 waves = gather workers.
// Publication: plane-major self-tagged u64s. plane[par][w][p], w=0..3:
//   w0 = batches 0-7 nibbles | tag, w1 = batches 8-15 | tag,
//   w2 = batches 16-23 | tag, w3 = batches 24-31 | tag   (tag = t+1 in hi32)
// Wave 1 polls plane 0 only (2 KB = 32 lines per round, 16x less poll traffic
// than R2); the post-barrier read pass re-verifies tags on all 4 planes
// (planes land ~simultaneously; expected 0 retries). Single-copy atomicity
// makes data+tag coherent -- no fences, no ordering chain. Parity
// double-buffer; overwrite-safe by the publish->consume lockstep argument.
__global__ __launch_bounds__(256) void scan_rsnn(const float* __restrict__ Iext,
                                                 const float* __restrict__ WP,
                                                 float* __restrict__ rate,
                                                 u64* planes) {
  __shared__ unsigned raw[4][NBLK];   // [batch-group][producer], bank = p%32: conflict-free
  __shared__ unsigned bm[32][32];     // [word w][batch b]
  __shared__ float psum[256];

  const int p    = blockIdx.x;
  const int tid  = threadIdx.x;
  const int wv   = tid >> 6;
  const int ln   = tid & 63;
  const int q    = tid & 127;        // gather pair (b,jj)
  const int half = tid >> 7;
  const int gb   = q >> 2;
  const int gjj  = q & 3;
  const float* wbase = WP + (size_t)p * (NH * SLICE) + gjj;

  // transpose assignment (identical to R2)
  const int cb   = tid & 31;
  const int cw0  = tid >> 5;
  const int csh  = 4 * (cb & 7);
  const int crow = cb >> 3;

  // wave-0 state: lane ln owns q0 = ln (batch b0 = ln>>2, jj = ln&3)
  //               and      q1 = ln+64 (batch b0+16, same jj)
  const int b0  = ln >> 2;
  const int col = SLICE * p + (ln & 3);

  const float D1 = 0.90483741803595957f;   // exp(-0.1)
  const float D2 = 0.81873075307798186f;   // exp(-0.2) == decay_syn

  float v0 = -60.0f, v1 = -60.0f;
  float A10 = 0.0f, A20 = 0.0f, A11 = 0.0f, A21 = 0.0f;
  float r0 = 0.0f, r1 = 0.0f, h0 = 0.0f, h1 = 0.0f, p0 = 0.0f, p1 = 0.0f;
  float ip0 = 0.0f, ip1 = 0.0f;
  int sc0 = 0, sc1 = 0;

  if (wv == 0) {
    ip0 = Iext[(size_t)b0 * NH + col];
    ip1 = Iext[(size_t)(b0 + 16) * NH + col];
  }

  for (int t = 0; t < T_STEPS; ++t) {
    const int par = t & 1;
    u64* pl = planes + (size_t)par * 4 * NBLK;

    if (wv == 0) {
      // ---- state update x2 (order of ops matches reference exactly) ----
      const float I0 = ip0 + p0;
      A10 *= D1; A20 *= D2;
      v0 = v0 + ((-60.0f - v0) / 20.0f + (I0 + A10 + A20) / 2.0f);
      const bool ir0 = r0 > 0.0f;
      if (ir0) v0 = -60.0f;
      const bool s0 = (!ir0) && (v0 >= -45.0f);
      if (s0) { v0 = -60.0f; A10 += 1.0f; A20 += -2.0f; r0 = 2.0f; sc0++; }
      else    { r0 = fmaxf(r0 - 1.0f, 0.0f); }

      const float I1 = ip1 + p1;
      A11 *= D1; A21 *= D2;
      v1 = v1 + ((-60.0f - v1) / 20.0f + (I1 + A11 + A21) / 2.0f);
      const bool ir1 = r1 > 0.0f;
      if (ir1) v1 = -60.0f;
      const bool s1 = (!ir1) && (v1 >= -45.0f);
      if (s1) { v1 = -60.0f; A11 += 1.0f; A21 += -2.0f; r1 = 2.0f; sc1++; }
      else    { r1 = fmaxf(r1 - 1.0f, 0.0f); }

      // bit ln = spike(q=ln) / spike(q=ln+64): same layout as R2's two waves
      const u64 bal0 = __ballot(s0);
      const u64 bal1 = __ballot(s1);
      if (ln == 0) {
        const u64 tagw = (u64)(unsigned)(t + 1) << 32;
        st64_agent(&pl[0 * NBLK + p], (u64)(unsigned)bal0         | tagw);
        st64_agent(&pl[1 * NBLK + p], (u64)(unsigned)(bal0 >> 32) | tagw);
        st64_agent(&pl[2 * NBLK + p], (u64)(unsigned)bal1         | tagw);
        st64_agent(&pl[3 * NBLK + p], (u64)(unsigned)(bal1 >> 32) | tagw);
      }
      __builtin_amdgcn_sched_barrier(0);   // keep prefetch from hoisting above publish
      // prefetch next step's external current (used next iteration)
      const int tn2 = (t + 1 < T_STEPS) ? t + 1 : t;
      ip0 = Iext[((size_t)tn2 * B_SZ + b0) * NH + col];
      ip1 = Iext[((size_t)tn2 * B_SZ + b0 + 16) * NH + col];
    } else if (wv == 1) {
      // ---- dedicated poll wave: plane 0, lane ln covers producers 4ln..4ln+3
      const u64 want = (u64)(unsigned)(t + 1);
      const u64* tp = &pl[0 * NBLK + 4 * ln];
      for (;;) {
        u64 q0_ = ld64_agent(tp + 0), q1_ = ld64_agent(tp + 1);
        u64 q2_ = ld64_agent(tp + 2), q3_ = ld64_agent(tp + 3);
        if (((q0_ >> 32) == want) & ((q1_ >> 32) == want) &
            ((q2_ >> 32) == want) & ((q3_ >> 32) == want)) break;
        __builtin_amdgcn_s_sleep(1);
      }
    }
    __syncthreads();   // P: publish issued + plane0 tags all detected

    // ---- one-shot read of all 4 planes (coalesced), verify tags, fill raw
    {
      const u64 want = (u64)(unsigned)(t + 1);
      u64 e0, e1, e2, e3;
      for (;;) {
        e0 = ld64_agent(&pl[0 * NBLK + tid]);
        e1 = ld64_agent(&pl[1 * NBLK + tid]);
        e2 = ld64_agent(&pl[2 * NBLK + tid]);
        e3 = ld64_agent(&pl[3 * NBLK + tid]);
        if (((e0 >> 32) == want) & ((e1 >> 32) == want) &
            ((e2 >> 32) == want) & ((e3 >> 32) == want)) break;
        __builtin_amdgcn_s_sleep(1);
      }
      raw[0][tid] = (unsigned)e0;
      raw[1][tid] = (unsigned)e1;
      raw[2][tid] = (unsigned)e2;
      raw[3][tid] = (unsigned)e3;
    }
    __syncthreads();   // T1

    // ---- transpose raw -> bm (identical to R2)
#pragma unroll
    for (int wi = 0; wi < 4; ++wi) {
      const int w = cw0 + 8 * wi;
      const unsigned* rr = &raw[crow][8 * w];
      unsigned u = 0;
#pragma unroll
      for (int k = 0; k < 8; ++k) u |= ((rr[k] >> csh) & 0xFu) << (4 * k);
      bm[w][cb] = u;
    }
    __syncthreads();   // T2

    // ---- sparse gather (identical to R2)
    float s = 0.0f;
    for (int w = half * 16; w < half * 16 + 16; ++w) {
      unsigned m = bm[w][gb];
      while (m) {
        const int bit = __builtin_ctz(m);
        m &= m - 1;
        s += wbase[(size_t)(w * 32 + bit) * SLICE];
      }
    }
    psum[tid] = s;
    __syncthreads();   // T3

    if (wv == 0) {
      // rec(q) = psum[q] + psum[q+128]: same summation order as R2
      const float rec0 = psum[ln] + psum[ln + 128];
      const float rec1 = psum[ln + 64] + psum[ln + 192];
      h0 = D2 * h0 + rec0;  p0 = D2 * p0 + h0;
      h1 = D2 * h1 + rec1;  p1 = D2 * p1 + h1;
    }
  }

  if (wv == 0) {
    rate[(size_t)b0 * NH + col]        = (float)sc0 / 1000.0f;
    rate[(size_t)(b0 + 16) * NH + col] = (float)sc1 / 1000.0f;
  }
}

// ---------------- kernel 4: out = rate @ W_out^T ----------------
__global__ __launch_bounds__(256) void out_gemv(const float* __restrict__ rate,
                                                const float* __restrict__ Wout,
                                                float* __restrict__ out) {
  __shared__ float rs[NH];
  const int b = blockIdx.x, tid = threadIdx.x;
  for (int i = tid; i < NH; i += 256) rs[i] = rate[(size_t)b * NH + i];
  __syncthreads();
  const float* wr = Wout + (size_t)tid * NH;
  float s = 0.0f;
  for (int hh = 0; hh < NH; hh += 4) {
    float4 w4 = *(const float4*)&wr[hh];
    s += rs[hh] * w4.x + rs[hh + 1] * w4.y + rs[hh + 2] * w4.z + rs[hh + 3] * w4.w;
  }
  out[(size_t)b * NO + tid] = s;
}

// ---------------- launch ----------------
extern "C" void kernel_launch(void* const* d_in, const int* in_sizes, int n_in,
                              void* d_out, int out_size, void* d_ws, size_t ws_size,
                              hipStream_t stream) {
  const float* x    = (const float*)d_in[0];
  const float* Win  = (const float*)d_in[1];
  const float* Wrec = (const float*)d_in[2];
  const float* Wout = (const float*)d_in[3];
  float* out = (float*)d_out;

  char* ws = (char*)d_ws;
  float* Iext = (float*)(ws + OFF_IEXT);
  float* WP   = (float*)(ws + OFF_WP);
  float* rate = (float*)(ws + OFF_RATE);
  u64*   planes = (u64*)(ws + OFF_SYNC);
  // No memset needed: 0xAA poison tag (0xAAAAAAAA) never equals t+1 <= 1000,
  // and every block publishes before polling -> no deadlock, no false match.

  prep_wp<<<dim3(NBLK), dim3(256), 0, stream>>>(Wrec, WP);
  gemm_in<<<dim3((T_STEPS * B_SZ) / GBM, NH / GBN), dim3(256), 0, stream>>>(x, Win, Iext);
  scan_rsnn<<<dim3(NBLK), dim3(256), 0, stream>>>(Iext, WP, rate, planes);
  out_gemv<<<dim3(B_SZ), dim3(256), 0, stream>>>(rate, Wout, out);
}

// Round 4
// 12462.250 us; speedup vs baseline: 1.0219x; 1.0219x over previous
//
#include <hip/hip_runtime.h>
#include <stdint.h>

// ---------------- problem constants ----------------
#define T_STEPS 1000
#define B_SZ    32
#define NI      512
#define NH      1024
#define NO      256

#define NBLK    256   // scan blocks; block p owns SLICE=4 postsyn neurons x all 32 batches
#define SLICE   4
#define NREP    16    // replication factor for the spike publication (contention / NREP)

typedef unsigned long long u64;

// ---------------- ws layout (bytes) ----------------
#define OFF_IEXT 0ull
#define SZ_IEXT  ((unsigned long long)T_STEPS * B_SZ * NH * 4ull)   // 131,072,000
#define OFF_WP   (OFF_IEXT + SZ_IEXT)
#define SZ_WP    ((unsigned long long)NH * NH * 4ull)               // 4 MiB
#define OFF_RATE (OFF_WP + SZ_WP)
#define SZ_RATE  ((unsigned long long)B_SZ * NH * 4ull)             // 128 KiB
#define OFF_SYNC (OFF_RATE + SZ_RATE)
#define SZ_SYNC  ((unsigned long long)2 * NREP * 4 * NBLK * 8ull)   // 256 KiB

// ---------------- agent-scope helpers ----------------
__device__ __forceinline__ u64 ld64_agent(const u64* p) {
  return __hip_atomic_load(p, __ATOMIC_RELAXED, __HIP_MEMORY_SCOPE_AGENT);
}
__device__ __forceinline__ void st64_agent(u64* p, u64 v) {
  __hip_atomic_store(p, v, __ATOMIC_RELAXED, __HIP_MEMORY_SCOPE_AGENT);
}

// ---------------- kernel 1: pack W_rec into per-block slices ----------------
// WP[(p*1024 + i)*4 + jj] = W_rec[(4p+jj)*1024 + i]  -> 16 KB contiguous per block
__global__ __launch_bounds__(256) void prep_wp(const float* __restrict__ Wrec,
                                               float* __restrict__ WP) {
  const int p = blockIdx.x;
  const int t = threadIdx.x;
#pragma unroll
  for (int it = 0; it < 4; ++it) {
    const int i = it * 256 + t;
    float4 w;
    w.x = Wrec[(size_t)(SLICE * p + 0) * NH + i];
    w.y = Wrec[(size_t)(SLICE * p + 1) * NH + i];
    w.z = Wrec[(size_t)(SLICE * p + 2) * NH + i];
    w.w = Wrec[(size_t)(SLICE * p + 3) * NH + i];
    ((float4*)WP)[(size_t)p * NH + i] = w;
  }
}

// ---------------- kernel 2: I_ext = x @ W_in^T  (fp32 tiled) ----------------
// Kept fp32 on purpose: bf16 I_ext (~0.2 abs err on ~N(0,50) values) would flip
// threshold crossings and cascade through the recurrence past the absmax budget.
#define GBM 128
#define GBN 128
#define GBK 16
__global__ __launch_bounds__(256) void gemm_in(const float* __restrict__ X,
                                               const float* __restrict__ Win,
                                               float* __restrict__ I) {
  __shared__ float As[GBK][GBM + 4];
  __shared__ float Bs[GBK][GBN + 4];
  const int tid = threadIdx.x;
  const int m0 = blockIdx.x * GBM;
  const int n0 = blockIdx.y * GBN;
  const int tm = tid >> 4, tn = tid & 15;
  const int lr = tid >> 1, lk = (tid & 1) * 8;
  float acc[8][8] = {};
  for (int k0 = 0; k0 < NI; k0 += GBK) {
    float4 a0 = *(const float4*)&X[(size_t)(m0 + lr) * NI + k0 + lk];
    float4 a1 = *(const float4*)&X[(size_t)(m0 + lr) * NI + k0 + lk + 4];
    float4 b0 = *(const float4*)&Win[(size_t)(n0 + lr) * NI + k0 + lk];
    float4 b1 = *(const float4*)&Win[(size_t)(n0 + lr) * NI + k0 + lk + 4];
    As[lk + 0][lr] = a0.x; As[lk + 1][lr] = a0.y; As[lk + 2][lr] = a0.z; As[lk + 3][lr] = a0.w;
    As[lk + 4][lr] = a1.x; As[lk + 5][lr] = a1.y; As[lk + 6][lr] = a1.z; As[lk + 7][lr] = a1.w;
    Bs[lk + 0][lr] = b0.x; Bs[lk + 1][lr] = b0.y; Bs[lk + 2][lr] = b0.z; Bs[lk + 3][lr] = b0.w;
    Bs[lk + 4][lr] = b1.x; Bs[lk + 5][lr] = b1.y; Bs[lk + 6][lr] = b1.z; Bs[lk + 7][lr] = b1.w;
    __syncthreads();
#pragma unroll
    for (int k = 0; k < GBK; ++k) {
      float av[8], bv[8];
      *(float4*)&av[0] = *(const float4*)&As[k][tm * 8];
      *(float4*)&av[4] = *(const float4*)&As[k][tm * 8 + 4];
      *(float4*)&bv[0] = *(const float4*)&Bs[k][tn * 8];
      *(float4*)&bv[4] = *(const float4*)&Bs[k][tn * 8 + 4];
#pragma unroll
      for (int i2 = 0; i2 < 8; ++i2)
#pragma unroll
        for (int j2 = 0; j2 < 8; ++j2) acc[i2][j2] += av[i2] * bv[j2];
    }
    __syncthreads();
  }
#pragma unroll
  for (int i2 = 0; i2 < 8; ++i2) {
    float4 c0 = {acc[i2][0], acc[i2][1], acc[i2][2], acc[i2][3]};
    float4 c1 = {acc[i2][4], acc[i2][5], acc[i2][6], acc[i2][7]};
    *(float4*)&I[(size_t)(m0 + tm * 8 + i2) * NH + n0 + tn * 8] = c0;
    *(float4*)&I[(size_t)(m0 + tm * 8 + i2) * NH + n0 + tn * 8 + 4] = c1;
  }
}

// ---------------- kernel 3: persistent 1000-step scan ----------------
// R1-R3 evidence: step time tracks max requests-per-LLC-line (~45 ns each,
// 256/line -> ~11.5 us/step). R4 replicates the publication NREP=16x so each
// line is shared by only 256/NREP = 16 consumer blocks.
//   planes[par][rep][w][p] (u64): lo32 = 32 spike bits, hi32 = tag (t+1).
//   w0 = batches 0-7 (nibbles = 4 neurons), w1 = 8-15, w2 = 16-23, w3 = 24-31.
// Producer: wave 0 lane ln stores replica ln>>2, word ln&3 (ballots are
// wave-uniform) -> one parallel store instruction publishes all 64 slots.
// Consumer block reads only replica p & 15. Wave 1 polls plane 0 of that
// replica; post-barrier read pass re-verifies tags on all 4 planes.
// Single-copy atomicity makes data+tag coherent; no fences. Parity
// double-buffer; overwrite-safe by the publish->consume lockstep argument.
__global__ __launch_bounds__(256) void scan_rsnn(const float* __restrict__ Iext,
                                                 const float* __restrict__ WP,
                                                 float* __restrict__ rate,
                                                 u64* planes) {
  __shared__ unsigned raw[4][NBLK + 4];  // +4 pad: crow stride 260 -> banks 0/4/8/12
  __shared__ unsigned bm[32][32];        // [word w][batch b]
  __shared__ float psum[256];

  const int p    = blockIdx.x;
  const int tid  = threadIdx.x;
  const int wv   = tid >> 6;
  const int ln   = tid & 63;
  const int q    = tid & 127;        // gather pair (b,jj)
  const int half = tid >> 7;
  const int gb   = q >> 2;
  const int gjj  = q & 3;
  const int myrep = p & (NREP - 1);
  const float* wbase = WP + (size_t)p * (NH * SLICE) + gjj;

  // transpose assignment (same mapping as R2/R3, verified)
  const int cb   = tid & 31;
  const int cw0  = tid >> 5;
  const int csh  = 4 * (cb & 7);
  const int crow = cb >> 3;

  // wave-0 state: lane ln owns q0 = ln (batch b0 = ln>>2, jj = ln&3)
  //               and      q1 = ln+64 (batch b0+16, same jj)
  const int b0  = ln >> 2;
  const int col = SLICE * p + (ln & 3);

  const float D1 = 0.90483741803595957f;   // exp(-0.1)
  const float D2 = 0.81873075307798186f;   // exp(-0.2) == decay_syn

  float v0 = -60.0f, v1 = -60.0f;
  float A10 = 0.0f, A20 = 0.0f, A11 = 0.0f, A21 = 0.0f;
  float r0 = 0.0f, r1 = 0.0f, h0 = 0.0f, h1 = 0.0f, p0 = 0.0f, p1 = 0.0f;
  float ip0 = 0.0f, ip1 = 0.0f;
  int sc0 = 0, sc1 = 0;

  if (wv == 0) {
    ip0 = Iext[(size_t)b0 * NH + col];
    ip1 = Iext[(size_t)(b0 + 16) * NH + col];
  }

  for (int t = 0; t < T_STEPS; ++t) {
    const int par = t & 1;
    u64* pl = planes + (size_t)par * (NREP * 4 * NBLK);

    if (wv == 0) {
      // ---- state update x2 (order of ops matches reference exactly) ----
      const float I0 = ip0 + p0;
      A10 *= D1; A20 *= D2;
      v0 = v0 + ((-60.0f - v0) / 20.0f + (I0 + A10 + A20) / 2.0f);
      const bool ir0 = r0 > 0.0f;
      if (ir0) v0 = -60.0f;
      const bool s0 = (!ir0) && (v0 >= -45.0f);
      if (s0) { v0 = -60.0f; A10 += 1.0f; A20 += -2.0f; r0 = 2.0f; sc0++; }
      else    { r0 = fmaxf(r0 - 1.0f, 0.0f); }

      const float I1 = ip1 + p1;
      A11 *= D1; A21 *= D2;
      v1 = v1 + ((-60.0f - v1) / 20.0f + (I1 + A11 + A21) / 2.0f);
      const bool ir1 = r1 > 0.0f;
      if (ir1) v1 = -60.0f;
      const bool s1 = (!ir1) && (v1 >= -45.0f);
      if (s1) { v1 = -60.0f; A11 += 1.0f; A21 += -2.0f; r1 = 2.0f; sc1++; }
      else    { r1 = fmaxf(r1 - 1.0f, 0.0f); }

      // ballots are wave-uniform: every lane publishes one (replica, word) slot
      const u64 bal0 = __ballot(s0);
      const u64 bal1 = __ballot(s1);
      {
        const u64 tagw = (u64)(unsigned)(t + 1) << 32;
        const int rep = ln >> 2;
        const int w   = ln & 3;
        const u64 bsel = (ln & 2) ? bal1 : bal0;
        const unsigned payload = (ln & 1) ? (unsigned)(bsel >> 32) : (unsigned)bsel;
        st64_agent(&pl[((size_t)(rep * 4 + w)) * NBLK + p], (u64)payload | tagw);
      }
      __builtin_amdgcn_sched_barrier(0);   // keep prefetch from hoisting above publish
      // prefetch next step's external current (used next iteration)
      const int tn2 = (t + 1 < T_STEPS) ? t + 1 : t;
      ip0 = Iext[((size_t)tn2 * B_SZ + b0) * NH + col];
      ip1 = Iext[((size_t)tn2 * B_SZ + b0 + 16) * NH + col];
    } else if (wv == 1) {
      // ---- dedicated poll wave: plane 0 of my replica; lane ln covers
      // producers 4ln..4ln+3 (32 B within one line; ~16 poller blocks/line)
      const u64 want = (u64)(unsigned)(t + 1);
      const u64* tp = &pl[((size_t)(myrep * 4 + 0)) * NBLK + 4 * ln];
      for (;;) {
        u64 q0_ = ld64_agent(tp + 0), q1_ = ld64_agent(tp + 1);
        u64 q2_ = ld64_agent(tp + 2), q3_ = ld64_agent(tp + 3);
        if (((q0_ >> 32) == want) & ((q1_ >> 32) == want) &
            ((q2_ >> 32) == want) & ((q3_ >> 32) == want)) break;
        __builtin_amdgcn_s_sleep(1);
      }
    }
    __syncthreads();   // P: publish issued + plane0 tags all detected

    // ---- one-shot coalesced read of all 4 planes of my replica, verify tags
    {
      const u64 want = (u64)(unsigned)(t + 1);
      u64 e0, e1, e2, e3;
      for (;;) {
        e0 = ld64_agent(&pl[((size_t)(myrep * 4 + 0)) * NBLK + tid]);
        e1 = ld64_agent(&pl[((size_t)(myrep * 4 + 1)) * NBLK + tid]);
        e2 = ld64_agent(&pl[((size_t)(myrep * 4 + 2)) * NBLK + tid]);
        e3 = ld64_agent(&pl[((size_t)(myrep * 4 + 3)) * NBLK + tid]);
        if (((e0 >> 32) == want) & ((e1 >> 32) == want) &
            ((e2 >> 32) == want) & ((e3 >> 32) == want)) break;
        __builtin_amdgcn_s_sleep(1);
      }
      raw[0][tid] = (unsigned)e0;
      raw[1][tid] = (unsigned)e1;
      raw[2][tid] = (unsigned)e2;
      raw[3][tid] = (unsigned)e3;
    }
    __syncthreads();   // T1

    // ---- transpose raw -> bm (mapping verified R2/R3)
#pragma unroll
    for (int wi = 0; wi < 4; ++wi) {
      const int w = cw0 + 8 * wi;
      const unsigned* rr = &raw[crow][8 * w];
      unsigned u = 0;
#pragma unroll
      for (int k = 0; k < 8; ++k) u |= ((rr[k] >> csh) & 0xFu) << (4 * k);
      bm[w][cb] = u;
    }
    __syncthreads();   // T2

    // ---- sparse gather: rec[b,j] = sum over spiking presyn i of W_rec[j,i]
    float s = 0.0f;
    for (int w = half * 16; w < half * 16 + 16; ++w) {
      unsigned m = bm[w][gb];
      while (m) {
        const int bit = __builtin_ctz(m);
        m &= m - 1;
        s += wbase[(size_t)(w * 32 + bit) * SLICE];
      }
    }
    psum[tid] = s;
    __syncthreads();   // T3

    if (wv == 0) {
      // rec(q) = psum[q] + psum[q+128]: same summation order as R2/R3
      const float rec0 = psum[ln] + psum[ln + 128];
      const float rec1 = psum[ln + 64] + psum[ln + 192];
      h0 = D2 * h0 + rec0;  p0 = D2 * p0 + h0;
      h1 = D2 * h1 + rec1;  p1 = D2 * p1 + h1;
    }
  }

  if (wv == 0) {
    rate[(size_t)b0 * NH + col]        = (float)sc0 / 1000.0f;
    rate[(size_t)(b0 + 16) * NH + col] = (float)sc1 / 1000.0f;
  }
}

// ---------------- kernel 4: out = rate @ W_out^T ----------------
__global__ __launch_bounds__(256) void out_gemv(const float* __restrict__ rate,
                                                const float* __restrict__ Wout,
                                                float* __restrict__ out) {
  __shared__ float rs[NH];
  const int b = blockIdx.x, tid = threadIdx.x;
  for (int i = tid; i < NH; i += 256) rs[i] = rate[(size_t)b * NH + i];
  __syncthreads();
  const float* wr = Wout + (size_t)tid * NH;
  float s = 0.0f;
  for (int hh = 0; hh < NH; hh += 4) {
    float4 w4 = *(const float4*)&wr[hh];
    s += rs[hh] * w4.x + rs[hh + 1] * w4.y + rs[hh + 2] * w4.z + rs[hh + 3] * w4.w;
  }
  out[(size_t)b * NO + tid] = s;
}

// ---------------- launch ----------------
extern "C" void kernel_launch(void* const* d_in, const int* in_sizes, int n_in,
                              void* d_out, int out_size, void* d_ws, size_t ws_size,
                              hipStream_t stream) {
  const float* x    = (const float*)d_in[0];
  const float* Win  = (const float*)d_in[1];
  const float* Wrec = (const float*)d_in[2];
  const float* Wout = (const float*)d_in[3];
  float* out = (float*)d_out;

  char* ws = (char*)d_ws;
  float* Iext = (float*)(ws + OFF_IEXT);
  float* WP   = (float*)(ws + OFF_WP);
  float* rate = (float*)(ws + OFF_RATE);
  u64*   planes = (u64*)(ws + OFF_SYNC);
  // No memset needed: 0xAA poison tag (0xAAAAAAAA) never equals t+1 <= 1000,
  // and every block publishes before polling -> no deadlock, no false match.

  prep_wp<<<dim3(NBLK), dim3(256), 0, stream>>>(Wrec, WP);
  gemm_in<<<dim3((T_STEPS * B_SZ) / GBM, NH / GBN), dim3(256), 0, stream>>>(x, Win, Iext);
  scan_rsnn<<<dim3(NBLK), dim3(256), 0, stream>>>(Iext, WP, rate, planes);
  out_gemv<<<dim3(B_SZ), dim3(256), 0, stream>>>(rate, Wout, out);
}

// Round 5
// 7294.446 us; speedup vs baseline: 1.7459x; 1.7085x over previous
//
#include <hip/hip_runtime.h>
#include <stdint.h>

// ---------------- problem constants ----------------
#define T_STEPS 1000
#define B_SZ    32
#define NI      512
#define NH      1024
#define NO      256

#define NSLICE  8     // neuron slices per batch; block (b,s) owns 128 neurons of batch b
#define NBLK    (B_SZ * NSLICE)   // 256 scan blocks

typedef unsigned long long u64;

// ---------------- ws layout (bytes) ----------------
#define OFF_IEXT 0ull
#define SZ_IEXT  ((unsigned long long)T_STEPS * B_SZ * NH * 4ull)   // 131,072,000
#define OFF_WTS  (OFF_IEXT + SZ_IEXT)
#define SZ_WTS   ((unsigned long long)NH * NH * 4ull)               // 4 MiB, WTS[s][i][jj]
#define OFF_RATE (OFF_WTS + SZ_WTS)
#define SZ_RATE  ((unsigned long long)B_SZ * NH * 4ull)             // 128 KiB
#define OFF_SYNC (OFF_RATE + SZ_RATE)
#define SZ_SYNC  ((unsigned long long)2 * B_SZ * NSLICE * 4 * 8ull) // 16 KiB

// ---------------- agent-scope helpers ----------------
__device__ __forceinline__ u64 ld64_agent(const u64* p) {
  return __hip_atomic_load(p, __ATOMIC_RELAXED, __HIP_MEMORY_SCOPE_AGENT);
}
__device__ __forceinline__ void st64_agent(u64* p, u64 v) {
  __hip_atomic_store(p, v, __ATOMIC_RELAXED, __HIP_MEMORY_SCOPE_AGENT);
}

// ---------------- kernel 1: transpose W_rec -> WTS ----------------
// WTS[(s*1024 + i)*128 + jj] = W_rec[(128s+jj)*1024 + i]
// Gather then reads contiguous 512B rows WTS[s][i][:]; slice s (512 KB) is
// shared by the 32 blocks of XCD s -> L2-resident.
__global__ __launch_bounds__(256) void prep_wts(const float* __restrict__ Wrec,
                                                float* __restrict__ WTS) {
  __shared__ float tile[64][65];
  const int tid = threadIdx.x;
  const int j0 = blockIdx.x * 64;           // 16 j-tiles
  const int i0 = blockIdx.y * 64;           // 16 i-tiles
  const int sl = j0 >> 7;
  const int jjb = j0 & 127;
#pragma unroll
  for (int k = 0; k < 16; ++k) {
    const int idx = k * 256 + tid;
    const int jl = idx >> 6, il = idx & 63;
    tile[jl][il] = Wrec[(size_t)(j0 + jl) * NH + i0 + il];
  }
  __syncthreads();
#pragma unroll
  for (int k = 0; k < 16; ++k) {
    const int idx = k * 256 + tid;
    const int il = idx >> 6, jl = idx & 63;
    WTS[((size_t)(sl * NH + i0 + il)) * 128 + jjb + jl] = tile[jl][il];
  }
}

// ---------------- kernel 2: I_ext = x @ W_in^T  (fp32 tiled) ----------------
// Kept fp32: bf16 I_ext would flip threshold crossings and cascade.
#define GBM 128
#define GBN 128
#define GBK 16
__global__ __launch_bounds__(256) void gemm_in(const float* __restrict__ X,
                                               const float* __restrict__ Win,
                                               float* __restrict__ I) {
  __shared__ float As[GBK][GBM + 4];
  __shared__ float Bs[GBK][GBN + 4];
  const int tid = threadIdx.x;
  const int m0 = blockIdx.x * GBM;
  const int n0 = blockIdx.y * GBN;
  const int tm = tid >> 4, tn = tid & 15;
  const int lr = tid >> 1, lk = (tid & 1) * 8;
  float acc[8][8] = {};
  for (int k0 = 0; k0 < NI; k0 += GBK) {
    float4 a0 = *(const float4*)&X[(size_t)(m0 + lr) * NI + k0 + lk];
    float4 a1 = *(const float4*)&X[(size_t)(m0 + lr) * NI + k0 + lk + 4];
    float4 b0 = *(const float4*)&Win[(size_t)(n0 + lr) * NI + k0 + lk];
    float4 b1 = *(const float4*)&Win[(size_t)(n0 + lr) * NI + k0 + lk + 4];
    As[lk + 0][lr] = a0.x; As[lk + 1][lr] = a0.y; As[lk + 2][lr] = a0.z; As[lk + 3][lr] = a0.w;
    As[lk + 4][lr] = a1.x; As[lk + 5][lr] = a1.y; As[lk + 6][lr] = a1.z; As[lk + 7][lr] = a1.w;
    Bs[lk + 0][lr] = b0.x; Bs[lk + 1][lr] = b0.y; Bs[lk + 2][lr] = b0.z; Bs[lk + 3][lr] = b0.w;
    Bs[lk + 4][lr] = b1.x; Bs[lk + 5][lr] = b1.y; Bs[lk + 6][lr] = b1.z; Bs[lk + 7][lr] = b1.w;
    __syncthreads();
#pragma unroll
    for (int k = 0; k < GBK; ++k) {
      float av[8], bv[8];
      *(float4*)&av[0] = *(const float4*)&As[k][tm * 8];
      *(float4*)&av[4] = *(const float4*)&As[k][tm * 8 + 4];
      *(float4*)&bv[0] = *(const float4*)&Bs[k][tn * 8];
      *(float4*)&bv[4] = *(const float4*)&Bs[k][tn * 8 + 4];
#pragma unroll
      for (int i2 = 0; i2 < 8; ++i2)
#pragma unroll
        for (int j2 = 0; j2 < 8; ++j2) acc[i2][j2] += av[i2] * bv[j2];
    }
    __syncthreads();
  }
#pragma unroll
  for (int i2 = 0; i2 < 8; ++i2) {
    float4 c0 = {acc[i2][0], acc[i2][1], acc[i2][2], acc[i2][3]};
    float4 c1 = {acc[i2][4], acc[i2][5], acc[i2][6], acc[i2][7]};
    *(float4*)&I[(size_t)(m0 + tm * 8 + i2) * NH + n0 + tn * 8] = c0;
    *(float4*)&I[(size_t)(m0 + tm * 8 + i2) * NH + n0 + tn * 8 + 4] = c1;
  }
}

// ---------------- kernel 3: persistent 1000-step scan, batch-diagonal ----------------
// Block (b, sl) = blockIdx b*8+sl: owns neurons j in [128*sl, 128*sl+128) of
// batch b. The recurrence is batch-diagonal, so sync is only among the 8
// blocks of a batch: 32 independent groups (no global lockstep; jitter in one
// group never stalls another). Publication: sync[par][b][sp][w] u64, lo32 =
// spikes of neurons 128*sp+32w..+31, hi32 = tag t+1 (single-copy atomic).
// Wave roles: waves 0-1 = 128 neuron states (1/lane) + publishers (2 lanes
// each); wave 2 = poller of the group's 32 words (detect == data arrival);
// all 4 waves gather (A-half words 0-15 on tid<128, B-half 16-31 on tid>=128).
__global__ __launch_bounds__(256) void scan_rsnn(const float* __restrict__ Iext,
                                                 const float* __restrict__ WTS,
                                                 float* __restrict__ rate,
                                                 u64* sync) {
  __shared__ unsigned bitmap[32];   // spike bitmap of batch b: word k = neurons 32k..32k+31
  __shared__ float psumB[128];

  const int bid = blockIdx.x;
  const int b   = bid >> 3;
  const int sl  = bid & 7;
  const int tid = threadIdx.x;
  const int wv  = tid >> 6;
  const int ln  = tid & 63;
  const int jloc = tid & 127;               // gather target j within slice

  const float* wts = WTS + (size_t)sl * NH * 128;

  const float D1 = 0.90483741803595957f;    // exp(-0.1)
  const float D2 = 0.81873075307798186f;    // exp(-0.2) == decay_syn

  // state (waves 0-1 only): neuron j = 128*sl + tid, tid<128
  float v = -60.0f, A1 = 0.0f, A2 = 0.0f, rf = 0.0f, h = 0.0f, psc = 0.0f;
  float ip = 0.0f;
  int sc = 0;

  if (tid < 128) ip = Iext[(size_t)b * NH + sl * 128 + tid];

  for (int t = 0; t < T_STEPS; ++t) {
    const int par = t & 1;
    u64* gbase = sync + ((size_t)(par * B_SZ + b)) * (NSLICE * 4);

    if (wv < 2) {
      // ---- state update (op order matches reference exactly) ----
      const float I = ip + psc;
      A1 *= D1; A2 *= D2;
      v = v + ((-60.0f - v) / 20.0f + (I + A1 + A2) / 2.0f);
      const bool inref = rf > 0.0f;
      if (inref) v = -60.0f;
      const bool spike = (!inref) && (v >= -45.0f);
      if (spike) { v = -60.0f; A1 += 1.0f; A2 += -2.0f; rf = 2.0f; sc++; }
      else       { rf = fmaxf(rf - 1.0f, 0.0f); }

      // ballot bit ln = spike(j = 128*sl + 64*wv + ln)
      const u64 bal = __ballot(spike);
      if (ln < 2) {
        const int w = wv * 2 + ln;          // word w covers neurons 128*sl+32w..
        const unsigned payload = ln ? (unsigned)(bal >> 32) : (unsigned)bal;
        st64_agent(&gbase[sl * 4 + w], (u64)payload | ((u64)(unsigned)(t + 1) << 32));
      }
      __builtin_amdgcn_sched_barrier(0);    // keep prefetch below the publish
      // prefetch next step's external current (512B contiguous per block)
      const int tn2 = (t + 1 < T_STEPS) ? t + 1 : t;
      ip = Iext[((size_t)tn2 * B_SZ + b) * NH + sl * 128 + tid];
    } else if (wv == 2) {
      // ---- poll the group's 32 words; payload+tag arrive together ----
      u64 val = 0;
      const u64* gp = &gbase[ln & 31];
      const unsigned want = (unsigned)(t + 1);
      for (;;) {
        if (ln < 32) val = ld64_agent(gp);
        const bool ok = (ln >= 32) || ((unsigned)(val >> 32) == want);
        if (__all(ok)) break;
      }
      if (ln < 32) bitmap[ln] = (unsigned)val;
    }
    __syncthreads();   // B1: bitmap ready

    // ---- sparse gather: rec[j] = sum over spiking presyn i of W_rec[j,i]
    // A-half (tid<128): words 0..15; B-half (tid>=128): words 16..31.
    float s = 0.0f;
    {
      const int w0 = (tid < 128) ? 0 : 16;
#pragma unroll 4
      for (int w = w0; w < w0 + 16; ++w) {
        unsigned m = bitmap[w];
        while (m) {
          const int bit = __builtin_ctz(m);
          m &= m - 1;
          s += wts[(size_t)(w * 32 + bit) * 128 + jloc];
        }
      }
    }
    if (tid >= 128) psumB[jloc] = s;
    __syncthreads();   // B2: B-half sums ready; also guards bitmap overwrite

    if (tid < 128) {
      const float rec = s + psumB[tid];     // same A+B order as R2-R4
      h = D2 * h + rec;
      psc = D2 * psc + h;                   // psc uses updated h (matches reference)
    }
  }

  if (tid < 128) rate[(size_t)b * NH + sl * 128 + tid] = (float)sc / 1000.0f;
}

// ---------------- kernel 4: out = rate @ W_out^T ----------------
__global__ __launch_bounds__(256) void out_gemv(const float* __restrict__ rate,
                                                const float* __restrict__ Wout,
                                                float* __restrict__ out) {
  __shared__ float rs[NH];
  const int b = blockIdx.x, tid = threadIdx.x;
  for (int i = tid; i < NH; i += 256) rs[i] = rate[(size_t)b * NH + i];
  __syncthreads();
  const float* wr = Wout + (size_t)tid * NH;
  float s = 0.0f;
  for (int hh = 0; hh < NH; hh += 4) {
    float4 w4 = *(const float4*)&wr[hh];
    s += rs[hh] * w4.x + rs[hh + 1] * w4.y + rs[hh + 2] * w4.z + rs[hh + 3] * w4.w;
  }
  out[(size_t)b * NO + tid] = s;
}

// ---------------- launch ----------------
extern "C" void kernel_launch(void* const* d_in, const int* in_sizes, int n_in,
                              void* d_out, int out_size, void* d_ws, size_t ws_size,
                              hipStream_t stream) {
  const float* x    = (const float*)d_in[0];
  const float* Win  = (const float*)d_in[1];
  const float* Wrec = (const float*)d_in[2];
  const float* Wout = (const float*)d_in[3];
  float* out = (float*)d_out;

  char* ws = (char*)d_ws;
  float* Iext = (float*)(ws + OFF_IEXT);
  float* WTS  = (float*)(ws + OFF_WTS);
  float* rate = (float*)(ws + OFF_RATE);
  u64*   sync = (u64*)(ws + OFF_SYNC);
  // No memset needed: 0xAA poison tag (0xAAAAAAAA) never equals t+1 <= 1000,
  // and every block publishes before its poll wave can block -> no deadlock.

  prep_wts<<<dim3(16, 16), dim3(256), 0, stream>>>(Wrec, WTS);
  gemm_in<<<dim3((T_STEPS * B_SZ) / GBM, NH / GBN), dim3(256), 0, stream>>>(x, Win, Iext);
  scan_rsnn<<<dim3(NBLK), dim3(256), 0, stream>>>(Iext, WTS, rate, sync);
  out_gemv<<<dim3(B_SZ), dim3(256), 0, stream>>>(rate, Wout, out);
}

// Round 6
// 3985.948 us; speedup vs baseline: 3.1951x; 1.8300x over previous
//
#include <hip/hip_runtime.h>
#include <stdint.h>

// ---------------- problem constants ----------------
#define T_STEPS 1000
#define B_SZ    32
#define NI      512
#define NH      1024
#define NO      256

#define NSLICE  8     // neuron slices per batch; block (b,s) owns 128 neurons of batch b
#define NBLK    (B_SZ * NSLICE)   // 256 scan blocks

typedef unsigned long long u64;

// ---------------- ws layout (bytes) ----------------
#define OFF_IEXT 0ull
#define SZ_IEXT  ((unsigned long long)T_STEPS * B_SZ * NH * 4ull)   // 131,072,000
#define OFF_WTS  (OFF_IEXT + SZ_IEXT)
#define SZ_WTS   ((unsigned long long)NH * NH * 4ull)               // 4 MiB, WTS[s][i][jj]
#define OFF_RATE (OFF_WTS + SZ_WTS)
#define SZ_RATE  ((unsigned long long)B_SZ * NH * 4ull)             // 128 KiB
#define OFF_SYNC (OFF_RATE + SZ_RATE)
#define SZ_SYNC  ((unsigned long long)2 * B_SZ * NSLICE * 4 * 8ull) // 16 KiB

// ---------------- agent-scope helpers ----------------
__device__ __forceinline__ u64 ld64_agent(const u64* p) {
  return __hip_atomic_load(p, __ATOMIC_RELAXED, __HIP_MEMORY_SCOPE_AGENT);
}
__device__ __forceinline__ void st64_agent(u64* p, u64 v) {
  __hip_atomic_store(p, v, __ATOMIC_RELAXED, __HIP_MEMORY_SCOPE_AGENT);
}

// ---------------- kernel 1: transpose W_rec -> WTS ----------------
// WTS[(s*1024 + i)*128 + jj] = W_rec[(128s+jj)*1024 + i]   (verified R5)
__global__ __launch_bounds__(256) void prep_wts(const float* __restrict__ Wrec,
                                                float* __restrict__ WTS) {
  __shared__ float tile[64][65];
  const int tid = threadIdx.x;
  const int j0 = blockIdx.x * 64;
  const int i0 = blockIdx.y * 64;
  const int sl = j0 >> 7;
  const int jjb = j0 & 127;
#pragma unroll
  for (int k = 0; k < 16; ++k) {
    const int idx = k * 256 + tid;
    const int jl = idx >> 6, il = idx & 63;
    tile[jl][il] = Wrec[(size_t)(j0 + jl) * NH + i0 + il];
  }
  __syncthreads();
#pragma unroll
  for (int k = 0; k < 16; ++k) {
    const int idx = k * 256 + tid;
    const int il = idx >> 6, jl = idx & 63;
    WTS[((size_t)(sl * NH + i0 + il)) * 128 + jjb + jl] = tile[jl][il];
  }
}

// ---------------- kernel 2: I_ext = x @ W_in^T  (fp32 tiled) ----------------
// Kept fp32: bf16 I_ext would flip threshold crossings and cascade.
#define GBM 128
#define GBN 128
#define GBK 16
__global__ __launch_bounds__(256) void gemm_in(const float* __restrict__ X,
                                               const float* __restrict__ Win,
                                               float* __restrict__ I) {
  __shared__ float As[GBK][GBM + 4];
  __shared__ float Bs[GBK][GBN + 4];
  const int tid = threadIdx.x;
  const int m0 = blockIdx.x * GBM;
  const int n0 = blockIdx.y * GBN;
  const int tm = tid >> 4, tn = tid & 15;
  const int lr = tid >> 1, lk = (tid & 1) * 8;
  float acc[8][8] = {};
  for (int k0 = 0; k0 < NI; k0 += GBK) {
    float4 a0 = *(const float4*)&X[(size_t)(m0 + lr) * NI + k0 + lk];
    float4 a1 = *(const float4*)&X[(size_t)(m0 + lr) * NI + k0 + lk + 4];
    float4 b0 = *(const float4*)&Win[(size_t)(n0 + lr) * NI + k0 + lk];
    float4 b1 = *(const float4*)&Win[(size_t)(n0 + lr) * NI + k0 + lk + 4];
    As[lk + 0][lr] = a0.x; As[lk + 1][lr] = a0.y; As[lk + 2][lr] = a0.z; As[lk + 3][lr] = a0.w;
    As[lk + 4][lr] = a1.x; As[lk + 5][lr] = a1.y; As[lk + 6][lr] = a1.z; As[lk + 7][lr] = a1.w;
    Bs[lk + 0][lr] = b0.x; Bs[lk + 1][lr] = b0.y; Bs[lk + 2][lr] = b0.z; Bs[lk + 3][lr] = b0.w;
    Bs[lk + 4][lr] = b1.x; Bs[lk + 5][lr] = b1.y; Bs[lk + 6][lr] = b1.z; Bs[lk + 7][lr] = b1.w;
    __syncthreads();
#pragma unroll
    for (int k = 0; k < GBK; ++k) {
      float av[8], bv[8];
      *(float4*)&av[0] = *(const float4*)&As[k][tm * 8];
      *(float4*)&av[4] = *(const float4*)&As[k][tm * 8 + 4];
      *(float4*)&bv[0] = *(const float4*)&Bs[k][tn * 8];
      *(float4*)&bv[4] = *(const float4*)&Bs[k][tn * 8 + 4];
#pragma unroll
      for (int i2 = 0; i2 < 8; ++i2)
#pragma unroll
        for (int j2 = 0; j2 < 8; ++j2) acc[i2][j2] += av[i2] * bv[j2];
    }
    __syncthreads();
  }
#pragma unroll
  for (int i2 = 0; i2 < 8; ++i2) {
    float4 c0 = {acc[i2][0], acc[i2][1], acc[i2][2], acc[i2][3]};
    float4 c1 = {acc[i2][4], acc[i2][5], acc[i2][6], acc[i2][7]};
    *(float4*)&I[(size_t)(m0 + tm * 8 + i2) * NH + n0 + tn * 8] = c0;
    *(float4*)&I[(size_t)(m0 + tm * 8 + i2) * NH + n0 + tn * 8 + 4] = c1;
  }
}

// ---------------- kernel 3: persistent 1000-step scan, batch-diagonal ----------------
// Structure as R5 (verified): block (b,sl) owns 128 neurons of batch b; sync
// only among the batch's 8 blocks. R6 change: wave 2 compacts the spike bitmap
// into an index list (same enumeration order: word-ascending, bit-ascending),
// and the gather runs 16 loads in flight, applying adds in list order --
// FP-identical to R5's serial while-loop, but ~16x the memory-level parallelism.
__global__ __launch_bounds__(256) void scan_rsnn(const float* __restrict__ Iext,
                                                 const float* __restrict__ WTS,
                                                 float* __restrict__ rate,
                                                 u64* sync) {
  __shared__ unsigned short slist[NH];  // compacted spike indices (worst case 1024)
  __shared__ int scnt[2];               // [0]=cntA (words 0-15), [1]=cnt total
  __shared__ float psumB[128];

  const int bid = blockIdx.x;
  const int b   = bid >> 3;
  const int sl  = bid & 7;
  const int tid = threadIdx.x;
  const int wv  = tid >> 6;
  const int ln  = tid & 63;
  const int jloc = tid & 127;               // gather target j within slice

  const float* wts = WTS + (size_t)sl * NH * 128;

  const float D1 = 0.90483741803595957f;    // exp(-0.1)
  const float D2 = 0.81873075307798186f;    // exp(-0.2) == decay_syn

  // state (waves 0-1 only): neuron j = 128*sl + tid, tid<128
  float v = -60.0f, A1 = 0.0f, A2 = 0.0f, rf = 0.0f, h = 0.0f, psc = 0.0f;
  float ip = 0.0f;
  int sc = 0;

  if (tid < 128) ip = Iext[(size_t)b * NH + sl * 128 + tid];

  for (int t = 0; t < T_STEPS; ++t) {
    const int par = t & 1;
    u64* gbase = sync + ((size_t)(par * B_SZ + b)) * (NSLICE * 4);

    if (wv < 2) {
      // ---- state update (op order matches reference exactly) ----
      const float I = ip + psc;
      A1 *= D1; A2 *= D2;
      v = v + ((-60.0f - v) / 20.0f + (I + A1 + A2) / 2.0f);
      const bool inref = rf > 0.0f;
      if (inref) v = -60.0f;
      const bool spike = (!inref) && (v >= -45.0f);
      if (spike) { v = -60.0f; A1 += 1.0f; A2 += -2.0f; rf = 2.0f; sc++; }
      else       { rf = fmaxf(rf - 1.0f, 0.0f); }

      // ballot bit ln = spike(j = 128*sl + 64*wv + ln)
      const u64 bal = __ballot(spike);
      if (ln < 2) {
        const int w = wv * 2 + ln;          // word w covers neurons 128*sl+32w..
        const unsigned payload = ln ? (unsigned)(bal >> 32) : (unsigned)bal;
        st64_agent(&gbase[sl * 4 + w], (u64)payload | ((u64)(unsigned)(t + 1) << 32));
      }
      __builtin_amdgcn_sched_barrier(0);    // keep prefetch below the publish
      // prefetch next step's external current (512B contiguous per block)
      const int tn2 = (t + 1 < T_STEPS) ? t + 1 : t;
      ip = Iext[((size_t)tn2 * B_SZ + b) * NH + sl * 128 + tid];
    } else if (wv == 2) {
      // ---- poll the batch's 32 words (detect == data arrival) ----
      u64 val = 0;
      const u64* gp = &gbase[ln & 31];
      const unsigned want = (unsigned)(t + 1);
      for (;;) {
        if (ln < 32) val = ld64_agent(gp);
        const bool ok = (ln >= 32) || ((unsigned)(val >> 32) == want);
        if (__all(ok)) break;
      }
      // ---- compact bitmap -> index list, same (word, bit) ascending order ----
      unsigned myw = (ln < 32) ? (unsigned)val : 0u;
      int inc = __popc(myw);
#pragma unroll
      for (int d = 1; d < 32; d <<= 1) {
        int y = __shfl_up(inc, d);
        if (ln >= d) inc += y;
      }
      const int cntA = __shfl(inc, 15);
      const int cnt  = __shfl(inc, 31);
      if (ln == 0) { scnt[0] = cntA; scnt[1] = cnt; }
      if (ln < 32) {
        int off = inc - __popc(myw);        // exclusive offset
        const int base = ln * 32;
        unsigned m = myw;
        while (m) {
          const int bit = __builtin_ctz(m);
          m &= m - 1;
          slist[off++] = (unsigned short)(base + bit);
        }
      }
    }
    __syncthreads();   // B1: slist/scnt ready

    // ---- sparse gather with 16-deep MLP; adds applied in list order ----
    // A-half (tid<128): entries [0, cntA) = words 0-15; B-half: [cntA, cnt).
    float s = 0.0f;
    {
      const int k0 = (tid < 128) ? 0 : scnt[0];
      const int k1 = (tid < 128) ? scnt[0] : scnt[1];
      int k = k0;
      for (; k + 16 <= k1; k += 16) {
        float wv16[16];
#pragma unroll
        for (int m2 = 0; m2 < 16; ++m2)
          wv16[m2] = wts[(size_t)slist[k + m2] * 128 + jloc];
#pragma unroll
        for (int m2 = 0; m2 < 16; ++m2) s += wv16[m2];   // in-order adds
      }
      for (; k < k1; ++k) s += wts[(size_t)slist[k] * 128 + jloc];
    }
    if (tid >= 128) psumB[jloc] = s;
    __syncthreads();   // B2: B-half sums ready; also guards slist overwrite

    if (tid < 128) {
      const float rec = s + psumB[tid];     // same A+B association as R2-R5
      h = D2 * h + rec;
      psc = D2 * psc + h;                   // psc uses updated h (matches reference)
    }
  }

  if (tid < 128) rate[(size_t)b * NH + sl * 128 + tid] = (float)sc / 1000.0f;
}

// ---------------- kernel 4: out = rate @ W_out^T ----------------
__global__ __launch_bounds__(256) void out_gemv(const float* __restrict__ rate,
                                                const float* __restrict__ Wout,
                                                float* __restrict__ out) {
  __shared__ float rs[NH];
  const int b = blockIdx.x, tid = threadIdx.x;
  for (int i = tid; i < NH; i += 256) rs[i] = rate[(size_t)b * NH + i];
  __syncthreads();
  const float* wr = Wout + (size_t)tid * NH;
  float s = 0.0f;
  for (int hh = 0; hh < NH; hh += 4) {
    float4 w4 = *(const float4*)&wr[hh];
    s += rs[hh] * w4.x + rs[hh + 1] * w4.y + rs[hh + 2] * w4.z + rs[hh + 3] * w4.w;
  }
  out[(size_t)b * NO + tid] = s;
}

// ---------------- launch ----------------
extern "C" void kernel_launch(void* const* d_in, const int* in_sizes, int n_in,
                              void* d_out, int out_size, void* d_ws, size_t ws_size,
                              hipStream_t stream) {
  const float* x    = (const float*)d_in[0];
  const float* Win  = (const float*)d_in[1];
  const float* Wrec = (const float*)d_in[2];
  const float* Wout = (const float*)d_in[3];
  float* out = (float*)d_out;

  char* ws = (char*)d_ws;
  float* Iext = (float*)(ws + OFF_IEXT);
  float* WTS  = (float*)(ws + OFF_WTS);
  float* rate = (float*)(ws + OFF_RATE);
  u64*   sync = (u64*)(ws + OFF_SYNC);
  // No memset needed: 0xAA poison tag (0xAAAAAAAA) never equals t+1 <= 1000,
  // and every block publishes before its poll wave can block -> no deadlock.

  prep_wts<<<dim3(16, 16), dim3(256), 0, stream>>>(Wrec, WTS);
  gemm_in<<<dim3((T_STEPS * B_SZ) / GBM, NH / GBN), dim3(256), 0, stream>>>(x, Win, Iext);
  scan_rsnn<<<dim3(NBLK), dim3(256), 0, stream>>>(Iext, WTS, rate, sync);
  out_gemv<<<dim3(B_SZ), dim3(256), 0, stream>>>(rate, Wout, out);
}